// Round 10
// baseline (265.391 us; speedup 1.0000x reference)
//
#include <hip/hip_runtime.h>
#include <hip/hip_bf16.h>

#define Bb 32
#define Nn 512
#define Cc 768
#define Hh 12
#define HDd 64
#define BND 358
// Q is pre-scaled by SCALE*log2(e) in the QKV epilogue -> logits in log2 domain
#define QS 0.18033688f

typedef unsigned short u16;
typedef unsigned int u32;
typedef __attribute__((ext_vector_type(8))) short bf16x8;
typedef __attribute__((ext_vector_type(4))) float f32x4;
typedef __attribute__((ext_vector_type(16))) float f32x16;
typedef __attribute__((ext_vector_type(4))) int i32x4;

__device__ __forceinline__ f32x4 MFMA16(bf16x8 a, bf16x8 b, f32x4 c) {
  return __builtin_amdgcn_mfma_f32_16x16x32_bf16(a, b, c, 0, 0, 0);
}
__device__ __forceinline__ f32x16 MFMA32(bf16x8 a, bf16x8 b, f32x16 c) {
  return __builtin_amdgcn_mfma_f32_32x32x16_bf16(a, b, c, 0, 0, 0);
}

__device__ __forceinline__ u32 f2bf(float f) {
  u32 u = __builtin_bit_cast(u32, f);
  return (u + 0x7fffu + ((u >> 16) & 1u)) >> 16;
}
__device__ __forceinline__ u32 packbf2(float a, float b) { return f2bf(a) | (f2bf(b) << 16); }
__device__ __forceinline__ u32 cvtpk2(float a, float b) {
  float2 f2 = {a, b};
  __hip_bfloat162 h = __float22bfloat162_rn(f2);   // v_cvt_pk_bf16_f32
  u32 r;
  __builtin_memcpy(&r, &h, 4);
  return r;
}
__device__ __forceinline__ float bf2f(u16 h) { return __builtin_bit_cast(float, (u32)h << 16); }

__device__ __forceinline__ void async_copy16(void* lds, const void* g) {
  __builtin_amdgcn_global_load_lds((const __attribute__((address_space(1))) void*)g,
                                   (__attribute__((address_space(3))) void*)lds, 16, 0, 0);
}

// ---------------- elementwise conversions ----------------

__global__ __launch_bounds__(256) void k_convx(const float* __restrict__ x, u16* __restrict__ xb) {
  int gid = blockIdx.x * 256 + threadIdx.x;
  if (gid >= (Bb * Nn * Cc) / 4) return;
  float4 v = *(const float4*)&x[gid * 4];
  u32 p0 = packbf2(v.x, v.y), p1 = packbf2(v.z, v.w);
  uint2 st = {p0, p1};
  *(uint2*)&xb[gid * 4] = st;
}

// src: R x Ccols fp32 row-major; dst: Ccols x R bf16 row-major (transpose+convert)
__global__ __launch_bounds__(256) void k_transpose(const float* __restrict__ src, u16* __restrict__ dst,
                                                   int R, int Ccols) {
  __shared__ float tbuf[32][33];
  int c0 = blockIdx.x * 32, r0 = blockIdx.y * 32;
  int lx = threadIdx.x & 31, ly = threadIdx.x >> 5;  // 32 x 8
  #pragma unroll
  for (int rr = ly; rr < 32; rr += 8) tbuf[rr][lx] = src[(long)(r0 + rr) * Ccols + c0 + lx];
  __syncthreads();
  #pragma unroll
  for (int cc = ly; cc < 32; cc += 8) dst[(long)(c0 + cc) * R + r0 + lx] = (u16)f2bf(tbuf[lx][cc]);
}

__global__ __launch_bounds__(256) void k_lens(const int* __restrict__ mask, int* __restrict__ lens) {
  int b = blockIdx.x, t = threadIdx.x;
  __shared__ int red[256];
  red[t] = mask[(long)b * Nn * Nn + t] + mask[(long)b * Nn * Nn + t + 256];
  __syncthreads();
  for (int s = 128; s > 0; s >>= 1) {
    if (t < s) red[t] += red[t + s];
    __syncthreads();
  }
  if (t == 0) lens[b] = red[0];
}

// Sort batches by len desc, then interleave long/short so contiguous block
// groups have balanced total work (shrinks the retirement tail).
__global__ void k_order(const int* __restrict__ lens, int* __restrict__ ord) {
  if (threadIdx.x == 0 && blockIdx.x == 0) {
    int idx[32];
    for (int i = 0; i < 32; ++i) idx[i] = i;
    for (int i = 1; i < 32; ++i) {
      int v = idx[i], lv = lens[v], j = i - 1;
      while (j >= 0 && lens[idx[j]] < lv) { idx[j + 1] = idx[j]; --j; }
      idx[j + 1] = v;
    }
    for (int s = 0; s < 32; ++s)
      ord[s] = (s & 1) ? idx[31 - (s >> 1)] : idx[s >> 1];
  }
}

// ---------------- GEMM v2: 128x128 tile, BK=64, double-buffered LDS ----------------
// MODE 0, SWAP 0 (V): stores V TILED: V[(bh)][qi>>5][d][qi&31] (32-key subtiles,
// each 64d x 32k contiguous 4KB).
template <int MODE, int SWAP>
__global__ __launch_bounds__(256) void k_gemm2(const u16* __restrict__ A, const u16* __restrict__ Bt,
                                               int nb0, u16* __restrict__ Qo, u16* __restrict__ Ko,
                                               u16* __restrict__ Vto, float* __restrict__ Co,
                                               const float* __restrict__ bias) {
  __shared__ u16 As[2][128 * 64];
  __shared__ u16 Bs[2][128 * 64];
  int m0 = blockIdx.x * 128;
  int nb = nb0 + blockIdx.y * 128;
  int t = threadIdx.x, lane = t & 63, wave = t >> 6;
  int wr = wave >> 1, wc = wave & 1;
  int qlane = lane & 15, g = lane >> 4;
  f32x4 acc[4][4] = {};

  auto stage = [&](int kt, int buf) {
    #pragma unroll
    for (int i = 0; i < 4; ++i) {
      int chunk = i * 256 + t;
      int row = chunk >> 3;
      int cp = (chunk & 7) << 4;
      int src = cp ^ ((row & 7) << 4);    // inverse-swizzled source byte-pos
      const u16* ga = A + (long)(m0 + row) * 768 + kt * 64 + (src >> 1);
      const u16* gb = Bt + (long)(nb + row) * 768 + kt * 64 + (src >> 1);
      async_copy16(&As[buf][(i * 256 + wave * 64) * 8], ga);
      async_copy16(&Bs[buf][(i * 256 + wave * 64) * 8], gb);
    }
  };

  auto compute = [&](int buf) {
    #pragma unroll
    for (int kk = 0; kk < 2; ++kk) {
      bf16x8 af[4], bf[4];
      #pragma unroll
      for (int x = 0; x < 4; ++x) {
        int ra = wr * 64 + x * 16 + qlane;
        int ca = (kk * 64 + g * 16) ^ ((ra & 7) << 4);   // swizzled read byte-pos
        af[x] = *(const bf16x8*)&As[buf][ra * 64 + (ca >> 1)];
        int rb = wc * 64 + x * 16 + qlane;
        int cb = (kk * 64 + g * 16) ^ ((rb & 7) << 4);
        bf[x] = *(const bf16x8*)&Bs[buf][rb * 64 + (cb >> 1)];
      }
      #pragma unroll
      for (int mi = 0; mi < 4; ++mi)
        #pragma unroll
        for (int ni = 0; ni < 4; ++ni)
          acc[mi][ni] = SWAP ? MFMA16(bf[ni], af[mi], acc[mi][ni])
                             : MFMA16(af[mi], bf[ni], acc[mi][ni]);
    }
  };

  stage(0, 0);
  __syncthreads();
  int cur = 0;
  for (int kt = 0; kt < 12; ++kt) {
    if (kt < 11) stage(kt + 1, cur ^ 1);
    compute(cur);
    __syncthreads();
    cur ^= 1;
  }

  if (MODE == 0 && SWAP == 1) {
    #pragma unroll
    for (int mi = 0; mi < 4; ++mi) {
      int m = m0 + wr * 64 + mi * 16 + qlane;
      int b = m >> 9, qi = m & 511;
      #pragma unroll
      for (int ni = 0; ni < 4; ++ni) {
        int nf = nb + wc * 64 + ni * 16 + g * 4;
        int which = nf >= 768;
        int rem = nf - which * 768;
        int hh = rem >> 6, d0 = rem & 63;
        u16* dst = (which ? Ko : Qo) + ((long)(b * Hh + hh) * Nn + qi) * HDd + d0;
        float sc = which ? 1.f : QS;   // pre-scale Q into log2 softmax domain
        uint2 st = {packbf2(acc[mi][ni][0] * sc, acc[mi][ni][1] * sc),
                    packbf2(acc[mi][ni][2] * sc, acc[mi][ni][3] * sc)};
        *(uint2*)dst = st;
      }
    }
  } else if (MODE == 0) {
    // V tiled: subtile = qi>>5 (4KB of 64d x 32k), within: d*32 + (qi&31)
    #pragma unroll
    for (int mi = 0; mi < 4; ++mi) {
      int m = m0 + wr * 64 + mi * 16 + g * 4;
      int b = m >> 9, qi = m & 511;
      #pragma unroll
      for (int ni = 0; ni < 4; ++ni) {
        int rem = nb + wc * 64 + ni * 16 + qlane - 1536;
        int hh = rem >> 6, d = rem & 63;
        u16* dst = Vto + (long)(b * Hh + hh) * (Nn * HDd) + (qi >> 5) * 2048 + d * 32 + (qi & 31);
        uint2 st = {packbf2(acc[mi][ni][0], acc[mi][ni][1]),
                    packbf2(acc[mi][ni][2], acc[mi][ni][3])};
        *(uint2*)dst = st;
      }
    }
  } else {
    #pragma unroll
    for (int mi = 0; mi < 4; ++mi) {
      #pragma unroll
      for (int ni = 0; ni < 4; ++ni) {
        int n = nb + wc * 64 + ni * 16 + qlane;
        float bv = bias[n];
        #pragma unroll
        for (int r = 0; r < 4; ++r) {
          int m = m0 + wr * 64 + mi * 16 + g * 4 + r;
          Co[(long)m * Cc + n] = acc[mi][ni][r] + bv;
        }
      }
    }
  }
}

// ---------------- fused attention v6: 1 wave/block + XCD grouping + 2-deep prefetch ----------------
// bid = chunk*384 + bh: all 8 q-chunks of one (b,h) share bid%8 -> same XCD L2
// (K/V fetched once per XCD). b = ord[bh/12] (len-interleaved) balances per-CU
// work. Register double-buffer (T14): tile t+1 loads issued before tile t compute.
__global__ __launch_bounds__(64) void k_attn(const u16* __restrict__ Q, const u16* __restrict__ K,
                                             const u16* __restrict__ Vt, const int* __restrict__ lens,
                                             const int* __restrict__ ord, u16* __restrict__ AO) {
  int lane = threadIdx.x;
  int bid = blockIdx.x;
  int bh = bid % (Bb * Hh);
  int chunk = bid / (Bb * Hh);
  int b = ord[bh / Hh];
  int h = bh % Hh;
  int q0w = chunk * 64;
  int ln = lane & 31, hi = lane >> 5;
  int len = lens[b];
  int nt = (len + 31) >> 5;

  const u16* Qb = Q + (long)(b * Hh + h) * Nn * HDd;
  const u16* Kb = K + (long)(b * Hh + h) * Nn * HDd;
  const u16* Vb = Vt + (long)(b * Hh + h) * Nn * HDd;  // tiled: 16 x (64d x 32k)

  // Q fragments: B-operand of mfma32 (Q^T): lane holds Q[q0+ln][ds*16+hi*8+j]
  bf16x8 qf[2][4];
  #pragma unroll
  for (int qt = 0; qt < 2; ++qt)
    #pragma unroll
    for (int ds = 0; ds < 4; ++ds)
      qf[qt][ds] = *(const bf16x8*)(Qb + (q0w + qt * 32 + ln) * HDd + ds * 16 + hi * 8);

  f32x16 o[2][2] = {};  // [qt][dt] : o^T[d][q], lane q=ln, 16 d-vals
  float l[2] = {0.f, 0.f};

  auto loadt = [&](bf16x8 (&kf)[4], bf16x8 (&vf)[2][2], int t) {
    int k0 = t * 32;
    #pragma unroll
    for (int ds = 0; ds < 4; ++ds)
      kf[ds] = *(const bf16x8*)(Kb + (k0 + ln) * HDd + ds * 16 + hi * 8);
    #pragma unroll
    for (int dt = 0; dt < 2; ++dt)
      #pragma unroll
      for (int ks = 0; ks < 2; ++ks)
        vf[dt][ks] = *(const bf16x8*)(Vb + t * 2048 + (dt * 32 + ln) * 32 + ks * 16 + hi * 8);
  };

  auto compute = [&](const bf16x8 (&kf)[4], const bf16x8 (&vf)[2][2], int t) {
    int k0 = t * 32;
    bool bdry = (k0 + 32 > len);
    int khi = k0 + 4 * hi;
    #pragma unroll
    for (int qt = 0; qt < 2; ++qt) {
      f32x16 st = {};
      #pragma unroll
      for (int ds = 0; ds < 4; ++ds) st = MFMA32(kf[ds], qf[qt][ds], st);
      // C-layout: row(key within 32) = (r&3)+8*(r>>2)+4*hi, col(q)=ln
      if (bdry) {
        #pragma unroll
        for (int r = 0; r < 16; ++r) {
          int key = khi + (r & 3) + 8 * (r >> 2);
          if (key >= len) st[r] = -1e9f;
        }
      }
      float p[16];
      #pragma unroll
      for (int r = 0; r < 16; ++r) p[r] = exp2f(st[r]);
      l[qt] += (((p[0] + p[1]) + (p[2] + p[3])) + ((p[4] + p[5]) + (p[6] + p[7]))) +
               (((p[8] + p[9]) + (p[10] + p[11])) + ((p[12] + p[13]) + (p[14] + p[15])));
      u32 wA0 = cvtpk2(p[0], p[1]), wA1 = cvtpk2(p[2], p[3]);
      u32 wA2 = cvtpk2(p[4], p[5]), wA3 = cvtpk2(p[6], p[7]);
      asm volatile("v_permlane32_swap_b32 %0, %1" : "+v"(wA0), "+v"(wA2));
      asm volatile("v_permlane32_swap_b32 %0, %1" : "+v"(wA1), "+v"(wA3));
      u32 wB0 = cvtpk2(p[8], p[9]), wB1 = cvtpk2(p[10], p[11]);
      u32 wB2 = cvtpk2(p[12], p[13]), wB3 = cvtpk2(p[14], p[15]);
      asm volatile("v_permlane32_swap_b32 %0, %1" : "+v"(wB0), "+v"(wB2));
      asm volatile("v_permlane32_swap_b32 %0, %1" : "+v"(wB1), "+v"(wB3));
      i32x4 bi0 = {(int)wA0, (int)wA1, (int)wA2, (int)wA3};
      i32x4 bi1 = {(int)wB0, (int)wB1, (int)wB2, (int)wB3};
      bf16x8 pb0 = __builtin_bit_cast(bf16x8, bi0);
      bf16x8 pb1 = __builtin_bit_cast(bf16x8, bi1);
      #pragma unroll
      for (int dt = 0; dt < 2; ++dt) {
        o[qt][dt] = MFMA32(vf[dt][0], pb0, o[qt][dt]);
        o[qt][dt] = MFMA32(vf[dt][1], pb1, o[qt][dt]);
      }
    }
  };

  // 2-deep software pipeline: named buffers (no runtime-indexed arrays)
  bf16x8 kfA[4], vfA[2][2], kfB[4], vfB[2][2];
  loadt(kfA, vfA, 0);
  int t = 0;
  #pragma unroll 1
  for (; t + 2 <= nt; t += 2) {
    loadt(kfB, vfB, t + 1);
    compute(kfA, vfA, t);
    if (t + 2 < nt) loadt(kfA, vfA, t + 2);
    compute(kfB, vfB, t + 1);
  }
  if (t < nt) compute(kfA, vfA, t);

  #pragma unroll
  for (int qt = 0; qt < 2; ++qt) {
    float ls = l[qt] + __shfl_xor(l[qt], 32);
    float inv = 1.f / ls;
    u16* outp = AO + ((long)(b * Nn + q0w + qt * 32 + ln) * Cc) + h * HDd;
    #pragma unroll
    for (int dt = 0; dt < 2; ++dt) {
      #pragma unroll
      for (int qd = 0; qd < 4; ++qd) {  // reg quad -> d = dt*32 + 8*qd + 4*hi + 0..3
        uint2 st2 = {cvtpk2(o[qt][dt][4 * qd + 0] * inv, o[qt][dt][4 * qd + 1] * inv),
                     cvtpk2(o[qt][dt][4 * qd + 2] * inv, o[qt][dt][4 * qd + 3] * inv)};
        *(uint2*)(outp + dt * 32 + 8 * qd + 4 * hi) = st2;
      }
    }
  }
}

// ---------------- CLS-row scores (one block per (b,h), atomic accumulate) ----------------
__global__ __launch_bounds__(256) void k_sco_init(float* __restrict__ sco) {
  int gid = blockIdx.x * 256 + threadIdx.x;
  if (gid < Bb * 511) sco[gid] = 0.f;
}

__global__ __launch_bounds__(256) void k_cls(const u16* __restrict__ Q, const u16* __restrict__ K,
                                             const int* __restrict__ lens, float* __restrict__ scores) {
  int bh = blockIdx.x;  // 0..383
  int b = bh / Hh;
  int t = threadIdx.x;
  int len = lens[b];
  __shared__ float qrow[64];
  __shared__ float red[256];
  const u16* Qb = Q + (long)bh * Nn * HDd;
  const u16* Kb = K + (long)bh * Nn * HDd;
  if (t < 64) qrow[t] = bf2f(Qb[t]);   // CLS query, pre-scaled (log2 domain)
  __syncthreads();
  const bf16x8* kr0 = (const bf16x8*)(Kb + t * HDd);
  const bf16x8* kr1 = (const bf16x8*)(Kb + (t + 256) * HDd);
  float d0 = 0.f, d1 = 0.f;
  #pragma unroll
  for (int c8 = 0; c8 < 8; ++c8) {
    bf16x8 kv0 = kr0[c8], kv1 = kr1[c8];
    #pragma unroll
    for (int j = 0; j < 8; ++j) {
      float qv = qrow[c8 * 8 + j];
      d0 += qv * bf2f((u16)kv0[j]);
      d1 += qv * bf2f((u16)kv1[j]);
    }
  }
  float l0 = (t < len) ? d0 : -1e9f;
  float l1 = (t + 256 < len) ? d1 : -1e9f;
  red[t] = fmaxf(l0, l1);
  __syncthreads();
  for (int ss = 128; ss > 0; ss >>= 1) {
    if (t < ss) red[t] = fmaxf(red[t], red[t + ss]);
    __syncthreads();
  }
  float mx = red[0];
  __syncthreads();
  float e0 = exp2f(l0 - mx), e1 = exp2f(l1 - mx);
  red[t] = e0 + e1;
  __syncthreads();
  for (int ss = 128; ss > 0; ss >>= 1) {
    if (t < ss) red[t] += red[t + ss];
    __syncthreads();
  }
  float w = (1.f / 12.f) / red[0];
  if (t >= 1) atomicAdd(&scores[b * 511 + (t - 1)], e0 * w);
  atomicAdd(&scores[b * 511 + (t + 255)], e1 * w);
}

// ---------------- top-k (bitonic sort 512, desc score / asc idx) ----------------
__device__ __forceinline__ bool sless(float sa, int ia, float sb, int ib) {
  return (sa > sb) || (sa == sb && ia < ib);
}

__global__ __launch_bounds__(256) void k_topk(const float* __restrict__ scores,
                                              const int* __restrict__ lens, float* __restrict__ dout) {
  int b = blockIdx.x, t = threadIdx.x;
  __shared__ float sc[512];
  __shared__ int id[512];
  float ninf = -__builtin_inff();
  int len = lens[b];
  for (int i = t; i < 512; i += 256) {
    sc[i] = (i < 511 && (i + 1) < len) ? scores[b * 511 + i] : ninf;
    id[i] = i;
  }
  for (int k = 2; k <= 512; k <<= 1) {
    for (int j = k >> 1; j > 0; j >>= 1) {
      __syncthreads();
      for (int i = t; i < 512; i += 256) {
        int ixj = i ^ j;
        if (ixj > i) {
          float si = sc[i], sj = sc[ixj];
          int ii = id[i], ij = id[ixj];
          bool up = ((i & k) == 0);
          bool dosw = up ? sless(sj, ij, si, ii) : sless(si, ii, sj, ij);
          if (dosw) {
            sc[i] = sj; sc[ixj] = si;
            id[i] = ij; id[ixj] = ii;
          }
        }
      }
    }
  }
  __syncthreads();
  int left = (int)ceilf((float)(len - 1) * 0.7f);
  const long OFF_IDX = (long)Bb * Nn * Cc + (long)Bb * BND * Cc;
  for (int p = t; p < BND; p += 256) {
    dout[OFF_IDX + (long)b * BND + p] = (p < left) ? (float)id[p] : 1e9f;
  }
  if (b == 0 && t == 0) dout[OFF_IDX + (long)Bb * BND] = (float)BND;
}

__global__ __launch_bounds__(256) void k_bcast(float* __restrict__ dout) {
  long gid = (long)blockIdx.x * 256 + threadIdx.x;
  const long total = (long)Bb * BND * (Cc / 4);
  if (gid >= total) return;
  long bp = gid / (Cc / 4);
  int c4 = (int)(gid % (Cc / 4));
  const long OFF_INDEX = (long)Bb * Nn * Cc;
  const long OFF_IDX = OFF_INDEX + (long)Bb * BND * Cc;
  float v = dout[OFF_IDX + bp];
  float4 f = {v, v, v, v};
  *(float4*)&dout[OFF_INDEX + bp * Cc + (long)c4 * 4] = f;
}

// ---------------- launch ----------------
extern "C" void kernel_launch(void* const* d_in, const int* in_sizes, int n_in,
                              void* d_out, int out_size, void* d_ws, size_t ws_size,
                              hipStream_t stream) {
  const float* x = (const float*)d_in[0];
  const int* mask = (const int*)d_in[1];
  const float* wqkv = (const float*)d_in[2];
  const float* wproj = (const float*)d_in[3];
  const float* bproj = (const float*)d_in[4];
  float* out = (float*)d_out;

  char* ws = (char*)d_ws;
  u16* Qw  = (u16*)(ws);                    // 25165824 B
  u16* Kw  = (u16*)(ws + 25165824L);        // 25165824 B
  u16* Vtw = (u16*)(ws + 50331648L);        // 25165824 B (tiled layout)
  u16* XB  = (u16*)(ws + 75497472L);        // 25165824 B (x bf16; reused as attn out)
  u16* AO  = XB;
  u16* WQT = (u16*)(ws + 100663296L);       // 3538944 B
  u16* WPT = (u16*)(ws + 104202240L);       // 1179648 B
  float* SCO = (float*)(ws + 105381888L);   // 65536 B
  int* LEN = (int*)(ws + 105447424L);       // 128 B
  int* ORD = (int*)(ws + 105447552L);       // 128 B

  k_convx<<<12288, 256, 0, stream>>>(x, XB);
  k_transpose<<<dim3(72, 24), 256, 0, stream>>>(wqkv, WQT, 768, 2304);
  k_transpose<<<dim3(24, 24), 256, 0, stream>>>(wproj, WPT, 768, 768);
  k_lens<<<32, 256, 0, stream>>>(mask, LEN);
  k_order<<<1, 64, 0, stream>>>(LEN, ORD);
  k_sco_init<<<64, 256, 0, stream>>>(SCO);
  k_gemm2<0, 1><<<dim3(128, 12), 256, 0, stream>>>(XB, WQT, 0, Qw, Kw, nullptr, nullptr, nullptr);
  k_gemm2<0, 0><<<dim3(128, 6), 256, 0, stream>>>(XB, WQT, 1536, nullptr, nullptr, Vtw, nullptr, nullptr);
  k_attn<<<3072, 64, 0, stream>>>(Qw, Kw, Vtw, LEN, ORD, AO);
  k_gemm2<1, 0><<<dim3(128, 6), 256, 0, stream>>>(AO, WPT, 0, nullptr, nullptr, nullptr, out, bproj);
  k_cls<<<384, 256, 0, stream>>>(Qw, Kw, LEN, SCO);
  k_topk<<<32, 256, 0, stream>>>(SCO, LEN, out);
  k_bcast<<<8592, 256, 0, stream>>>(out);
}

// Round 11
// 232.177 us; speedup vs baseline: 1.1431x; 1.1431x over previous
//
#include <hip/hip_runtime.h>
#include <hip/hip_bf16.h>

#define Bb 32
#define Nn 512
#define Cc 768
#define Hh 12
#define HDd 64
#define BND 358
// Q is pre-scaled by SCALE*log2(e) in the QKV epilogue -> logits in log2 domain
#define QS 0.18033688f

typedef unsigned short u16;
typedef unsigned int u32;
typedef __attribute__((ext_vector_type(8))) short bf16x8;
typedef __attribute__((ext_vector_type(4))) float f32x4;
typedef __attribute__((ext_vector_type(16))) float f32x16;
typedef __attribute__((ext_vector_type(4))) int i32x4;

__device__ __forceinline__ f32x4 MFMA16(bf16x8 a, bf16x8 b, f32x4 c) {
  return __builtin_amdgcn_mfma_f32_16x16x32_bf16(a, b, c, 0, 0, 0);
}
__device__ __forceinline__ f32x16 MFMA32(bf16x8 a, bf16x8 b, f32x16 c) {
  return __builtin_amdgcn_mfma_f32_32x32x16_bf16(a, b, c, 0, 0, 0);
}

__device__ __forceinline__ u32 f2bf(float f) {
  u32 u = __builtin_bit_cast(u32, f);
  return (u + 0x7fffu + ((u >> 16) & 1u)) >> 16;
}
__device__ __forceinline__ u32 packbf2(float a, float b) { return f2bf(a) | (f2bf(b) << 16); }
__device__ __forceinline__ u32 cvtpk2(float a, float b) {
  float2 f2 = {a, b};
  __hip_bfloat162 h = __float22bfloat162_rn(f2);   // v_cvt_pk_bf16_f32
  u32 r;
  __builtin_memcpy(&r, &h, 4);
  return r;
}
__device__ __forceinline__ float bf2f(u16 h) { return __builtin_bit_cast(float, (u32)h << 16); }

__device__ __forceinline__ void async_copy16(void* lds, const void* g) {
  __builtin_amdgcn_global_load_lds((const __attribute__((address_space(1))) void*)g,
                                   (__attribute__((address_space(3))) void*)lds, 16, 0, 0);
}

// ---------------- elementwise conversions ----------------

__global__ __launch_bounds__(256) void k_convx(const float* __restrict__ x, u16* __restrict__ xb) {
  int gid = blockIdx.x * 256 + threadIdx.x;
  if (gid >= (Bb * Nn * Cc) / 4) return;
  float4 v = *(const float4*)&x[gid * 4];
  u32 p0 = packbf2(v.x, v.y), p1 = packbf2(v.z, v.w);
  uint2 st = {p0, p1};
  *(uint2*)&xb[gid * 4] = st;
}

// src: R x Ccols fp32 row-major; dst: Ccols x R bf16 row-major (transpose+convert)
__global__ __launch_bounds__(256) void k_transpose(const float* __restrict__ src, u16* __restrict__ dst,
                                                   int R, int Ccols) {
  __shared__ float tbuf[32][33];
  int c0 = blockIdx.x * 32, r0 = blockIdx.y * 32;
  int lx = threadIdx.x & 31, ly = threadIdx.x >> 5;  // 32 x 8
  #pragma unroll
  for (int rr = ly; rr < 32; rr += 8) tbuf[rr][lx] = src[(long)(r0 + rr) * Ccols + c0 + lx];
  __syncthreads();
  #pragma unroll
  for (int cc = ly; cc < 32; cc += 8) dst[(long)(c0 + cc) * R + r0 + lx] = (u16)f2bf(tbuf[lx][cc]);
}

__global__ __launch_bounds__(256) void k_lens(const int* __restrict__ mask, int* __restrict__ lens) {
  int b = blockIdx.x, t = threadIdx.x;
  __shared__ int red[256];
  red[t] = mask[(long)b * Nn * Nn + t] + mask[(long)b * Nn * Nn + t + 256];
  __syncthreads();
  for (int s = 128; s > 0; s >>= 1) {
    if (t < s) red[t] += red[t + s];
    __syncthreads();
  }
  if (t == 0) lens[b] = red[0];
}

// Parallel rank-sort: each thread computes its batch's rank (desc len, asc idx
// tiebreak) and writes the long/short-interleaved slot directly. O(32)/thread.
__global__ __launch_bounds__(64) void k_order(const int* __restrict__ lens, int* __restrict__ ord) {
  __shared__ int ls[32];
  int t = threadIdx.x;
  if (t < 32) ls[t] = lens[t];
  __syncthreads();
  if (t < 32) {
    int mylen = ls[t];
    int rank = 0;
    #pragma unroll
    for (int j = 0; j < 32; ++j) {
      int lj = ls[j];
      rank += (lj > mylen || (lj == mylen && j < t)) ? 1 : 0;
    }
    int s = (rank < 16) ? (2 * rank) : (2 * (31 - rank) + 1);
    ord[s] = t;
  }
}

// ---------------- GEMM v2: 128x128 tile, BK=64, double-buffered LDS ----------------
// MODE 0, SWAP 0 (V): stores V TILED: V[(bh)][qi>>5][d][qi&31] (32-key subtiles,
// each 64d x 32k contiguous 4KB).
template <int MODE, int SWAP>
__global__ __launch_bounds__(256) void k_gemm2(const u16* __restrict__ A, const u16* __restrict__ Bt,
                                               int nb0, u16* __restrict__ Qo, u16* __restrict__ Ko,
                                               u16* __restrict__ Vto, float* __restrict__ Co,
                                               const float* __restrict__ bias) {
  __shared__ u16 As[2][128 * 64];
  __shared__ u16 Bs[2][128 * 64];
  int m0 = blockIdx.x * 128;
  int nb = nb0 + blockIdx.y * 128;
  int t = threadIdx.x, lane = t & 63, wave = t >> 6;
  int wr = wave >> 1, wc = wave & 1;
  int qlane = lane & 15, g = lane >> 4;
  f32x4 acc[4][4] = {};

  auto stage = [&](int kt, int buf) {
    #pragma unroll
    for (int i = 0; i < 4; ++i) {
      int chunk = i * 256 + t;
      int row = chunk >> 3;
      int cp = (chunk & 7) << 4;
      int src = cp ^ ((row & 7) << 4);    // inverse-swizzled source byte-pos
      const u16* ga = A + (long)(m0 + row) * 768 + kt * 64 + (src >> 1);
      const u16* gb = Bt + (long)(nb + row) * 768 + kt * 64 + (src >> 1);
      async_copy16(&As[buf][(i * 256 + wave * 64) * 8], ga);
      async_copy16(&Bs[buf][(i * 256 + wave * 64) * 8], gb);
    }
  };

  auto compute = [&](int buf) {
    #pragma unroll
    for (int kk = 0; kk < 2; ++kk) {
      bf16x8 af[4], bf[4];
      #pragma unroll
      for (int x = 0; x < 4; ++x) {
        int ra = wr * 64 + x * 16 + qlane;
        int ca = (kk * 64 + g * 16) ^ ((ra & 7) << 4);   // swizzled read byte-pos
        af[x] = *(const bf16x8*)&As[buf][ra * 64 + (ca >> 1)];
        int rb = wc * 64 + x * 16 + qlane;
        int cb = (kk * 64 + g * 16) ^ ((rb & 7) << 4);
        bf[x] = *(const bf16x8*)&Bs[buf][rb * 64 + (cb >> 1)];
      }
      #pragma unroll
      for (int mi = 0; mi < 4; ++mi)
        #pragma unroll
        for (int ni = 0; ni < 4; ++ni)
          acc[mi][ni] = SWAP ? MFMA16(bf[ni], af[mi], acc[mi][ni])
                             : MFMA16(af[mi], bf[ni], acc[mi][ni]);
    }
  };

  stage(0, 0);
  __syncthreads();
  int cur = 0;
  for (int kt = 0; kt < 12; ++kt) {
    if (kt < 11) stage(kt + 1, cur ^ 1);
    compute(cur);
    __syncthreads();
    cur ^= 1;
  }

  if (MODE == 0 && SWAP == 1) {
    #pragma unroll
    for (int mi = 0; mi < 4; ++mi) {
      int m = m0 + wr * 64 + mi * 16 + qlane;
      int b = m >> 9, qi = m & 511;
      #pragma unroll
      for (int ni = 0; ni < 4; ++ni) {
        int nf = nb + wc * 64 + ni * 16 + g * 4;
        int which = nf >= 768;
        int rem = nf - which * 768;
        int hh = rem >> 6, d0 = rem & 63;
        u16* dst = (which ? Ko : Qo) + ((long)(b * Hh + hh) * Nn + qi) * HDd + d0;
        float sc = which ? 1.f : QS;   // pre-scale Q into log2 softmax domain
        uint2 st = {packbf2(acc[mi][ni][0] * sc, acc[mi][ni][1] * sc),
                    packbf2(acc[mi][ni][2] * sc, acc[mi][ni][3] * sc)};
        *(uint2*)dst = st;
      }
    }
  } else if (MODE == 0) {
    // V tiled: subtile = qi>>5 (4KB of 64d x 32k), within: d*32 + (qi&31)
    #pragma unroll
    for (int mi = 0; mi < 4; ++mi) {
      int m = m0 + wr * 64 + mi * 16 + g * 4;
      int b = m >> 9, qi = m & 511;
      #pragma unroll
      for (int ni = 0; ni < 4; ++ni) {
        int rem = nb + wc * 64 + ni * 16 + qlane - 1536;
        int hh = rem >> 6, d = rem & 63;
        u16* dst = Vto + (long)(b * Hh + hh) * (Nn * HDd) + (qi >> 5) * 2048 + d * 32 + (qi & 31);
        uint2 st = {packbf2(acc[mi][ni][0], acc[mi][ni][1]),
                    packbf2(acc[mi][ni][2], acc[mi][ni][3])};
        *(uint2*)dst = st;
      }
    }
  } else {
    #pragma unroll
    for (int mi = 0; mi < 4; ++mi) {
      #pragma unroll
      for (int ni = 0; ni < 4; ++ni) {
        int n = nb + wc * 64 + ni * 16 + qlane;
        float bv = bias[n];
        #pragma unroll
        for (int r = 0; r < 4; ++r) {
          int m = m0 + wr * 64 + mi * 16 + g * 4 + r;
          Co[(long)m * Cc + n] = acc[mi][ni][r] + bv;
        }
      }
    }
  }
}

// ---------------- fused attention v7: 4 independent waves/block (no barriers) ----------------
// 768 blocks x 256 threads. Wave w handles chunk half*4+w of the SAME (b,h):
// 4 waves walk identical K/V tiles near-lockstep on one CU -> L1 hits, and
// 4x fewer workgroups cuts dispatch/drain pressure. 384 % 8 == 0 keeps both
// blocks of a (b,h) on one XCD. b = ord[..] (len-interleaved) balances work.
__global__ __launch_bounds__(256) void k_attn(const u16* __restrict__ Q, const u16* __restrict__ K,
                                              const u16* __restrict__ Vt, const int* __restrict__ lens,
                                              const int* __restrict__ ord, u16* __restrict__ AO) {
  int lane = threadIdx.x & 63;
  int wave = threadIdx.x >> 6;
  int bid = blockIdx.x;
  int bh = bid % (Bb * Hh);
  int half = bid / (Bb * Hh);
  int b = ord[bh / Hh];
  int h = bh % Hh;
  int chunk = half * 4 + wave;
  int q0w = chunk * 64;
  int ln = lane & 31, hi = lane >> 5;
  int len = lens[b];
  int nt = (len + 31) >> 5;

  const u16* Qb = Q + (long)(b * Hh + h) * Nn * HDd;
  const u16* Kb = K + (long)(b * Hh + h) * Nn * HDd;
  const u16* Vb = Vt + (long)(b * Hh + h) * Nn * HDd;  // tiled: 16 x (64d x 32k)

  // Q fragments: B-operand of mfma32 (Q^T): lane holds Q[q0+ln][ds*16+hi*8+j]
  bf16x8 qf[2][4];
  #pragma unroll
  for (int qt = 0; qt < 2; ++qt)
    #pragma unroll
    for (int ds = 0; ds < 4; ++ds)
      qf[qt][ds] = *(const bf16x8*)(Qb + (q0w + qt * 32 + ln) * HDd + ds * 16 + hi * 8);

  f32x16 o[2][2] = {};  // [qt][dt] : o^T[d][q], lane q=ln, 16 d-vals
  float l[2] = {0.f, 0.f};

  auto loadt = [&](bf16x8 (&kf)[4], bf16x8 (&vf)[2][2], int t) {
    int k0 = t * 32;
    #pragma unroll
    for (int ds = 0; ds < 4; ++ds)
      kf[ds] = *(const bf16x8*)(Kb + (k0 + ln) * HDd + ds * 16 + hi * 8);
    #pragma unroll
    for (int dt = 0; dt < 2; ++dt)
      #pragma unroll
      for (int ks = 0; ks < 2; ++ks)
        vf[dt][ks] = *(const bf16x8*)(Vb + t * 2048 + (dt * 32 + ln) * 32 + ks * 16 + hi * 8);
  };

  auto compute = [&](const bf16x8 (&kf)[4], const bf16x8 (&vf)[2][2], int t) {
    int k0 = t * 32;
    bool bdry = (k0 + 32 > len);
    int khi = k0 + 4 * hi;
    #pragma unroll
    for (int qt = 0; qt < 2; ++qt) {
      f32x16 st = {};
      #pragma unroll
      for (int ds = 0; ds < 4; ++ds) st = MFMA32(kf[ds], qf[qt][ds], st);
      // C-layout: row(key within 32) = (r&3)+8*(r>>2)+4*hi, col(q)=ln
      if (bdry) {
        #pragma unroll
        for (int r = 0; r < 16; ++r) {
          int key = khi + (r & 3) + 8 * (r >> 2);
          if (key >= len) st[r] = -1e9f;
        }
      }
      float p[16];
      #pragma unroll
      for (int r = 0; r < 16; ++r) p[r] = exp2f(st[r]);
      l[qt] += (((p[0] + p[1]) + (p[2] + p[3])) + ((p[4] + p[5]) + (p[6] + p[7]))) +
               (((p[8] + p[9]) + (p[10] + p[11])) + ((p[12] + p[13]) + (p[14] + p[15])));
      u32 wA0 = cvtpk2(p[0], p[1]), wA1 = cvtpk2(p[2], p[3]);
      u32 wA2 = cvtpk2(p[4], p[5]), wA3 = cvtpk2(p[6], p[7]);
      asm volatile("v_permlane32_swap_b32 %0, %1" : "+v"(wA0), "+v"(wA2));
      asm volatile("v_permlane32_swap_b32 %0, %1" : "+v"(wA1), "+v"(wA3));
      u32 wB0 = cvtpk2(p[8], p[9]), wB1 = cvtpk2(p[10], p[11]);
      u32 wB2 = cvtpk2(p[12], p[13]), wB3 = cvtpk2(p[14], p[15]);
      asm volatile("v_permlane32_swap_b32 %0, %1" : "+v"(wB0), "+v"(wB2));
      asm volatile("v_permlane32_swap_b32 %0, %1" : "+v"(wB1), "+v"(wB3));
      i32x4 bi0 = {(int)wA0, (int)wA1, (int)wA2, (int)wA3};
      i32x4 bi1 = {(int)wB0, (int)wB1, (int)wB2, (int)wB3};
      bf16x8 pb0 = __builtin_bit_cast(bf16x8, bi0);
      bf16x8 pb1 = __builtin_bit_cast(bf16x8, bi1);
      #pragma unroll
      for (int dt = 0; dt < 2; ++dt) {
        o[qt][dt] = MFMA32(vf[dt][0], pb0, o[qt][dt]);
        o[qt][dt] = MFMA32(vf[dt][1], pb1, o[qt][dt]);
      }
    }
  };

  // 2-deep software pipeline: named buffers (no runtime-indexed arrays)
  bf16x8 kfA[4], vfA[2][2], kfB[4], vfB[2][2];
  loadt(kfA, vfA, 0);
  int t = 0;
  #pragma unroll 1
  for (; t + 2 <= nt; t += 2) {
    loadt(kfB, vfB, t + 1);
    compute(kfA, vfA, t);
    if (t + 2 < nt) loadt(kfA, vfA, t + 2);
    compute(kfB, vfB, t + 1);
  }
  if (t < nt) compute(kfA, vfA, t);

  #pragma unroll
  for (int qt = 0; qt < 2; ++qt) {
    float ls = l[qt] + __shfl_xor(l[qt], 32);
    float inv = 1.f / ls;
    u16* outp = AO + ((long)(b * Nn + q0w + qt * 32 + ln) * Cc) + h * HDd;
    #pragma unroll
    for (int dt = 0; dt < 2; ++dt) {
      #pragma unroll
      for (int qd = 0; qd < 4; ++qd) {  // reg quad -> d = dt*32 + 8*qd + 4*hi + 0..3
        uint2 st2 = {cvtpk2(o[qt][dt][4 * qd + 0] * inv, o[qt][dt][4 * qd + 1] * inv),
                     cvtpk2(o[qt][dt][4 * qd + 2] * inv, o[qt][dt][4 * qd + 3] * inv)};
        *(uint2*)(outp + dt * 32 + 8 * qd + 4 * hi) = st2;
      }
    }
  }
}

// ---------------- CLS-row scores (one block per (b,h), atomic accumulate) ----------------
__global__ __launch_bounds__(256) void k_sco_init(float* __restrict__ sco) {
  int gid = blockIdx.x * 256 + threadIdx.x;
  if (gid < Bb * 511) sco[gid] = 0.f;
}

__global__ __launch_bounds__(256) void k_cls(const u16* __restrict__ Q, const u16* __restrict__ K,
                                             const int* __restrict__ lens, float* __restrict__ scores) {
  int bh = blockIdx.x;  // 0..383
  int b = bh / Hh;
  int t = threadIdx.x;
  int len = lens[b];
  __shared__ float qrow[64];
  __shared__ float red[256];
  const u16* Qb = Q + (long)bh * Nn * HDd;
  const u16* Kb = K + (long)bh * Nn * HDd;
  if (t < 64) qrow[t] = bf2f(Qb[t]);   // CLS query, pre-scaled (log2 domain)
  __syncthreads();
  const bf16x8* kr0 = (const bf16x8*)(Kb + t * HDd);
  const bf16x8* kr1 = (const bf16x8*)(Kb + (t + 256) * HDd);
  float d0 = 0.f, d1 = 0.f;
  #pragma unroll
  for (int c8 = 0; c8 < 8; ++c8) {
    bf16x8 kv0 = kr0[c8], kv1 = kr1[c8];
    #pragma unroll
    for (int j = 0; j < 8; ++j) {
      float qv = qrow[c8 * 8 + j];
      d0 += qv * bf2f((u16)kv0[j]);
      d1 += qv * bf2f((u16)kv1[j]);
    }
  }
  float l0 = (t < len) ? d0 : -1e9f;
  float l1 = (t + 256 < len) ? d1 : -1e9f;
  red[t] = fmaxf(l0, l1);
  __syncthreads();
  for (int ss = 128; ss > 0; ss >>= 1) {
    if (t < ss) red[t] = fmaxf(red[t], red[t + ss]);
    __syncthreads();
  }
  float mx = red[0];
  __syncthreads();
  float e0 = exp2f(l0 - mx), e1 = exp2f(l1 - mx);
  red[t] = e0 + e1;
  __syncthreads();
  for (int ss = 128; ss > 0; ss >>= 1) {
    if (t < ss) red[t] += red[t + ss];
    __syncthreads();
  }
  float w = (1.f / 12.f) / red[0];
  if (t >= 1) atomicAdd(&scores[b * 511 + (t - 1)], e0 * w);
  atomicAdd(&scores[b * 511 + (t + 255)], e1 * w);
}

// ---------------- top-k (bitonic sort 512, desc score / asc idx) ----------------
__device__ __forceinline__ bool sless(float sa, int ia, float sb, int ib) {
  return (sa > sb) || (sa == sb && ia < ib);
}

__global__ __launch_bounds__(256) void k_topk(const float* __restrict__ scores,
                                              const int* __restrict__ lens, float* __restrict__ dout) {
  int b = blockIdx.x, t = threadIdx.x;
  __shared__ float sc[512];
  __shared__ int id[512];
  float ninf = -__builtin_inff();
  int len = lens[b];
  for (int i = t; i < 512; i += 256) {
    sc[i] = (i < 511 && (i + 1) < len) ? scores[b * 511 + i] : ninf;
    id[i] = i;
  }
  for (int k = 2; k <= 512; k <<= 1) {
    for (int j = k >> 1; j > 0; j >>= 1) {
      __syncthreads();
      for (int i = t; i < 512; i += 256) {
        int ixj = i ^ j;
        if (ixj > i) {
          float si = sc[i], sj = sc[ixj];
          int ii = id[i], ij = id[ixj];
          bool up = ((i & k) == 0);
          bool dosw = up ? sless(sj, ij, si, ii) : sless(si, ii, sj, ij);
          if (dosw) {
            sc[i] = sj; sc[ixj] = si;
            id[i] = ij; id[ixj] = ii;
          }
        }
      }
    }
  }
  __syncthreads();
  int left = (int)ceilf((float)(len - 1) * 0.7f);
  const long OFF_IDX = (long)Bb * Nn * Cc + (long)Bb * BND * Cc;
  for (int p = t; p < BND; p += 256) {
    dout[OFF_IDX + (long)b * BND + p] = (p < left) ? (float)id[p] : 1e9f;
  }
  if (b == 0 && t == 0) dout[OFF_IDX + (long)Bb * BND] = (float)BND;
}

__global__ __launch_bounds__(256) void k_bcast(float* __restrict__ dout) {
  long gid = (long)blockIdx.x * 256 + threadIdx.x;
  const long total = (long)Bb * BND * (Cc / 4);
  if (gid >= total) return;
  long bp = gid / (Cc / 4);
  int c4 = (int)(gid % (Cc / 4));
  const long OFF_INDEX = (long)Bb * Nn * Cc;
  const long OFF_IDX = OFF_INDEX + (long)Bb * BND * Cc;
  float v = dout[OFF_IDX + bp];
  float4 f = {v, v, v, v};
  *(float4*)&dout[OFF_INDEX + bp * Cc + (long)c4 * 4] = f;
}

// ---------------- launch ----------------
extern "C" void kernel_launch(void* const* d_in, const int* in_sizes, int n_in,
                              void* d_out, int out_size, void* d_ws, size_t ws_size,
                              hipStream_t stream) {
  const float* x = (const float*)d_in[0];
  const int* mask = (const int*)d_in[1];
  const float* wqkv = (const float*)d_in[2];
  const float* wproj = (const float*)d_in[3];
  const float* bproj = (const float*)d_in[4];
  float* out = (float*)d_out;

  char* ws = (char*)d_ws;
  u16* Qw  = (u16*)(ws);                    // 25165824 B
  u16* Kw  = (u16*)(ws + 25165824L);        // 25165824 B
  u16* Vtw = (u16*)(ws + 50331648L);        // 25165824 B (tiled layout)
  u16* XB  = (u16*)(ws + 75497472L);        // 25165824 B (x bf16; reused as attn out)
  u16* AO  = XB;
  u16* WQT = (u16*)(ws + 100663296L);       // 3538944 B
  u16* WPT = (u16*)(ws + 104202240L);       // 1179648 B
  float* SCO = (float*)(ws + 105381888L);   // 65536 B
  int* LEN = (int*)(ws + 105447424L);       // 128 B
  int* ORD = (int*)(ws + 105447552L);       // 128 B

  k_convx<<<12288, 256, 0, stream>>>(x, XB);
  k_transpose<<<dim3(72, 24), 256, 0, stream>>>(wqkv, WQT, 768, 2304);
  k_transpose<<<dim3(24, 24), 256, 0, stream>>>(wproj, WPT, 768, 768);
  k_lens<<<32, 256, 0, stream>>>(mask, LEN);
  k_order<<<1, 64, 0, stream>>>(LEN, ORD);
  k_sco_init<<<64, 256, 0, stream>>>(SCO);
  k_gemm2<0, 1><<<dim3(128, 12), 256, 0, stream>>>(XB, WQT, 0, Qw, Kw, nullptr, nullptr, nullptr);
  k_gemm2<0, 0><<<dim3(128, 6), 256, 0, stream>>>(XB, WQT, 1536, nullptr, nullptr, Vtw, nullptr, nullptr);
  k_attn<<<768, 256, 0, stream>>>(Qw, Kw, Vtw, LEN, ORD, AO);
  k_gemm2<1, 0><<<dim3(128, 6), 256, 0, stream>>>(AO, WPT, 0, nullptr, nullptr, nullptr, out, bproj);
  k_cls<<<384, 256, 0, stream>>>(Qw, Kw, LEN, SCO);
  k_topk<<<32, 256, 0, stream>>>(SCO, LEN, out);
  k_bcast<<<8592, 256, 0, stream>>>(out);
}

// Round 12
// 217.479 us; speedup vs baseline: 1.2203x; 1.0676x over previous
//
#include <hip/hip_runtime.h>
#include <hip/hip_bf16.h>

#define Bb 32
#define Nn 512
#define Cc 768
#define Hh 12
#define HDd 64
#define BND 358
// Q is pre-scaled by SCALE*log2(e) in the QKV epilogue -> logits in log2 domain
#define QS 0.18033688f

typedef unsigned short u16;
typedef unsigned int u32;
typedef __attribute__((ext_vector_type(8))) short bf16x8;
typedef __attribute__((ext_vector_type(4))) float f32x4;
typedef __attribute__((ext_vector_type(16))) float f32x16;
typedef __attribute__((ext_vector_type(4))) int i32x4;

__device__ __forceinline__ f32x4 MFMA16(bf16x8 a, bf16x8 b, f32x4 c) {
  return __builtin_amdgcn_mfma_f32_16x16x32_bf16(a, b, c, 0, 0, 0);
}
__device__ __forceinline__ f32x16 MFMA32(bf16x8 a, bf16x8 b, f32x16 c) {
  return __builtin_amdgcn_mfma_f32_32x32x16_bf16(a, b, c, 0, 0, 0);
}

__device__ __forceinline__ float fexp2(float x) { return __builtin_amdgcn_exp2f(x); }  // raw v_exp_f32

__device__ __forceinline__ u32 f2bf(float f) {
  u32 u = __builtin_bit_cast(u32, f);
  return (u + 0x7fffu + ((u >> 16) & 1u)) >> 16;
}
__device__ __forceinline__ u32 packbf2(float a, float b) { return f2bf(a) | (f2bf(b) << 16); }
__device__ __forceinline__ u32 cvtpk2(float a, float b) {
  float2 f2 = {a, b};
  __hip_bfloat162 h = __float22bfloat162_rn(f2);   // v_cvt_pk_bf16_f32
  u32 r;
  __builtin_memcpy(&r, &h, 4);
  return r;
}
__device__ __forceinline__ float bf2f(u16 h) { return __builtin_bit_cast(float, (u32)h << 16); }

__device__ __forceinline__ void async_copy16(void* lds, const void* g) {
  __builtin_amdgcn_global_load_lds((const __attribute__((address_space(1))) void*)g,
                                   (__attribute__((address_space(3))) void*)lds, 16, 0, 0);
}

// ---------------- elementwise conversions ----------------

__global__ __launch_bounds__(256) void k_convx(const float* __restrict__ x, u16* __restrict__ xb) {
  int gid = blockIdx.x * 256 + threadIdx.x;
  if (gid >= (Bb * Nn * Cc) / 4) return;
  float4 v = *(const float4*)&x[gid * 4];
  u32 p0 = packbf2(v.x, v.y), p1 = packbf2(v.z, v.w);
  uint2 st = {p0, p1};
  *(uint2*)&xb[gid * 4] = st;
}

// src: R x Ccols fp32 row-major; dst: Ccols x R bf16 row-major (transpose+convert)
__global__ __launch_bounds__(256) void k_transpose(const float* __restrict__ src, u16* __restrict__ dst,
                                                   int R, int Ccols) {
  __shared__ float tbuf[32][33];
  int c0 = blockIdx.x * 32, r0 = blockIdx.y * 32;
  int lx = threadIdx.x & 31, ly = threadIdx.x >> 5;  // 32 x 8
  #pragma unroll
  for (int rr = ly; rr < 32; rr += 8) tbuf[rr][lx] = src[(long)(r0 + rr) * Ccols + c0 + lx];
  __syncthreads();
  #pragma unroll
  for (int cc = ly; cc < 32; cc += 8) dst[(long)(c0 + cc) * R + r0 + lx] = (u16)f2bf(tbuf[lx][cc]);
}

__global__ __launch_bounds__(256) void k_lens(const int* __restrict__ mask, int* __restrict__ lens) {
  int b = blockIdx.x, t = threadIdx.x;
  __shared__ int red[256];
  red[t] = mask[(long)b * Nn * Nn + t] + mask[(long)b * Nn * Nn + t + 256];
  __syncthreads();
  for (int s = 128; s > 0; s >>= 1) {
    if (t < s) red[t] += red[t + s];
    __syncthreads();
  }
  if (t == 0) lens[b] = red[0];
}

// Parallel rank-sort: each thread computes its batch's rank (desc len, asc idx
// tiebreak) and writes the long/short-interleaved slot directly. O(32)/thread.
__global__ __launch_bounds__(64) void k_order(const int* __restrict__ lens, int* __restrict__ ord) {
  __shared__ int ls[32];
  int t = threadIdx.x;
  if (t < 32) ls[t] = lens[t];
  __syncthreads();
  if (t < 32) {
    int mylen = ls[t];
    int rank = 0;
    #pragma unroll
    for (int j = 0; j < 32; ++j) {
      int lj = ls[j];
      rank += (lj > mylen || (lj == mylen && j < t)) ? 1 : 0;
    }
    int s = (rank < 16) ? (2 * rank) : (2 * (31 - rank) + 1);
    ord[s] = t;
  }
}

// ---------------- GEMM v2: 128x128 tile, BK=64, double-buffered LDS ----------------
// MODE 0, SWAP 0 (V): stores V TILED: V[(bh)][qi>>5][d][qi&31] (32-key subtiles,
// each 64d x 32k contiguous 4KB).
template <int MODE, int SWAP>
__global__ __launch_bounds__(256) void k_gemm2(const u16* __restrict__ A, const u16* __restrict__ Bt,
                                               int nb0, u16* __restrict__ Qo, u16* __restrict__ Ko,
                                               u16* __restrict__ Vto, float* __restrict__ Co,
                                               const float* __restrict__ bias) {
  __shared__ u16 As[2][128 * 64];
  __shared__ u16 Bs[2][128 * 64];
  int m0 = blockIdx.x * 128;
  int nb = nb0 + blockIdx.y * 128;
  int t = threadIdx.x, lane = t & 63, wave = t >> 6;
  int wr = wave >> 1, wc = wave & 1;
  int qlane = lane & 15, g = lane >> 4;
  f32x4 acc[4][4] = {};

  auto stage = [&](int kt, int buf) {
    #pragma unroll
    for (int i = 0; i < 4; ++i) {
      int chunk = i * 256 + t;
      int row = chunk >> 3;
      int cp = (chunk & 7) << 4;
      int src = cp ^ ((row & 7) << 4);    // inverse-swizzled source byte-pos
      const u16* ga = A + (long)(m0 + row) * 768 + kt * 64 + (src >> 1);
      const u16* gb = Bt + (long)(nb + row) * 768 + kt * 64 + (src >> 1);
      async_copy16(&As[buf][(i * 256 + wave * 64) * 8], ga);
      async_copy16(&Bs[buf][(i * 256 + wave * 64) * 8], gb);
    }
  };

  auto compute = [&](int buf) {
    #pragma unroll
    for (int kk = 0; kk < 2; ++kk) {
      bf16x8 af[4], bf[4];
      #pragma unroll
      for (int x = 0; x < 4; ++x) {
        int ra = wr * 64 + x * 16 + qlane;
        int ca = (kk * 64 + g * 16) ^ ((ra & 7) << 4);   // swizzled read byte-pos
        af[x] = *(const bf16x8*)&As[buf][ra * 64 + (ca >> 1)];
        int rb = wc * 64 + x * 16 + qlane;
        int cb = (kk * 64 + g * 16) ^ ((rb & 7) << 4);
        bf[x] = *(const bf16x8*)&Bs[buf][rb * 64 + (cb >> 1)];
      }
      #pragma unroll
      for (int mi = 0; mi < 4; ++mi)
        #pragma unroll
        for (int ni = 0; ni < 4; ++ni)
          acc[mi][ni] = SWAP ? MFMA16(bf[ni], af[mi], acc[mi][ni])
                             : MFMA16(af[mi], bf[ni], acc[mi][ni]);
    }
  };

  stage(0, 0);
  __syncthreads();
  int cur = 0;
  for (int kt = 0; kt < 12; ++kt) {
    if (kt < 11) stage(kt + 1, cur ^ 1);
    compute(cur);
    __syncthreads();
    cur ^= 1;
  }

  if (MODE == 0 && SWAP == 1) {
    #pragma unroll
    for (int mi = 0; mi < 4; ++mi) {
      int m = m0 + wr * 64 + mi * 16 + qlane;
      int b = m >> 9, qi = m & 511;
      #pragma unroll
      for (int ni = 0; ni < 4; ++ni) {
        int nf = nb + wc * 64 + ni * 16 + g * 4;
        int which = nf >= 768;
        int rem = nf - which * 768;
        int hh = rem >> 6, d0 = rem & 63;
        u16* dst = (which ? Ko : Qo) + ((long)(b * Hh + hh) * Nn + qi) * HDd + d0;
        float sc = which ? 1.f : QS;   // pre-scale Q into log2 softmax domain
        uint2 st = {packbf2(acc[mi][ni][0] * sc, acc[mi][ni][1] * sc),
                    packbf2(acc[mi][ni][2] * sc, acc[mi][ni][3] * sc)};
        *(uint2*)dst = st;
      }
    }
  } else if (MODE == 0) {
    // V tiled: subtile = qi>>5 (4KB of 64d x 32k), within: d*32 + (qi&31)
    #pragma unroll
    for (int mi = 0; mi < 4; ++mi) {
      int m = m0 + wr * 64 + mi * 16 + g * 4;
      int b = m >> 9, qi = m & 511;
      #pragma unroll
      for (int ni = 0; ni < 4; ++ni) {
        int rem = nb + wc * 64 + ni * 16 + qlane - 1536;
        int hh = rem >> 6, d = rem & 63;
        u16* dst = Vto + (long)(b * Hh + hh) * (Nn * HDd) + (qi >> 5) * 2048 + d * 32 + (qi & 31);
        uint2 st = {packbf2(acc[mi][ni][0], acc[mi][ni][1]),
                    packbf2(acc[mi][ni][2], acc[mi][ni][3])};
        *(uint2*)dst = st;
      }
    }
  } else {
    #pragma unroll
    for (int mi = 0; mi < 4; ++mi) {
      #pragma unroll
      for (int ni = 0; ni < 4; ++ni) {
        int n = nb + wc * 64 + ni * 16 + qlane;
        float bv = bias[n];
        #pragma unroll
        for (int r = 0; r < 4; ++r) {
          int m = m0 + wr * 64 + mi * 16 + g * 4 + r;
          Co[(long)m * Cc + n] = acc[mi][ni][r] + bv;
        }
      }
    }
  }
}

// ---------------- fused attention v8: R10 grid + raw v_exp_f32 ----------------
// 3072 one-wave blocks. bid = chunk*384 + bh: all 8 q-chunks of one (b,h) share
// bid%8 -> same XCD L2. b = ord[..] (len-interleaved) balances per-CU work.
// 2-deep register prefetch (named buffers). exp2 = single v_exp_f32.
__global__ __launch_bounds__(64) void k_attn(const u16* __restrict__ Q, const u16* __restrict__ K,
                                             const u16* __restrict__ Vt, const int* __restrict__ lens,
                                             const int* __restrict__ ord, u16* __restrict__ AO) {
  int lane = threadIdx.x;
  int bid = blockIdx.x;
  int bh = bid % (Bb * Hh);
  int chunk = bid / (Bb * Hh);
  int b = ord[bh / Hh];
  int h = bh % Hh;
  int q0w = chunk * 64;
  int ln = lane & 31, hi = lane >> 5;
  int len = lens[b];
  int nt = (len + 31) >> 5;

  const u16* Qb = Q + (long)(b * Hh + h) * Nn * HDd;
  const u16* Kb = K + (long)(b * Hh + h) * Nn * HDd;
  const u16* Vb = Vt + (long)(b * Hh + h) * Nn * HDd;  // tiled: 16 x (64d x 32k)

  // Q fragments: B-operand of mfma32 (Q^T): lane holds Q[q0+ln][ds*16+hi*8+j]
  bf16x8 qf[2][4];
  #pragma unroll
  for (int qt = 0; qt < 2; ++qt)
    #pragma unroll
    for (int ds = 0; ds < 4; ++ds)
      qf[qt][ds] = *(const bf16x8*)(Qb + (q0w + qt * 32 + ln) * HDd + ds * 16 + hi * 8);

  f32x16 o[2][2] = {};  // [qt][dt] : o^T[d][q], lane q=ln, 16 d-vals
  float l[2] = {0.f, 0.f};

  auto loadt = [&](bf16x8 (&kf)[4], bf16x8 (&vf)[2][2], int t) {
    int k0 = t * 32;
    #pragma unroll
    for (int ds = 0; ds < 4; ++ds)
      kf[ds] = *(const bf16x8*)(Kb + (k0 + ln) * HDd + ds * 16 + hi * 8);
    #pragma unroll
    for (int dt = 0; dt < 2; ++dt)
      #pragma unroll
      for (int ks = 0; ks < 2; ++ks)
        vf[dt][ks] = *(const bf16x8*)(Vb + t * 2048 + (dt * 32 + ln) * 32 + ks * 16 + hi * 8);
  };

  auto compute = [&](const bf16x8 (&kf)[4], const bf16x8 (&vf)[2][2], int t) {
    int k0 = t * 32;
    bool bdry = (k0 + 32 > len);
    int khi = k0 + 4 * hi;
    #pragma unroll
    for (int qt = 0; qt < 2; ++qt) {
      f32x16 st = {};
      #pragma unroll
      for (int ds = 0; ds < 4; ++ds) st = MFMA32(kf[ds], qf[qt][ds], st);
      // C-layout: row(key within 32) = (r&3)+8*(r>>2)+4*hi, col(q)=ln
      if (bdry) {
        #pragma unroll
        for (int r = 0; r < 16; ++r) {
          int key = khi + (r & 3) + 8 * (r >> 2);
          if (key >= len) st[r] = -1e9f;
        }
      }
      float p[16];
      #pragma unroll
      for (int r = 0; r < 16; ++r) p[r] = fexp2(st[r]);
      l[qt] += (((p[0] + p[1]) + (p[2] + p[3])) + ((p[4] + p[5]) + (p[6] + p[7]))) +
               (((p[8] + p[9]) + (p[10] + p[11])) + ((p[12] + p[13]) + (p[14] + p[15])));
      u32 wA0 = cvtpk2(p[0], p[1]), wA1 = cvtpk2(p[2], p[3]);
      u32 wA2 = cvtpk2(p[4], p[5]), wA3 = cvtpk2(p[6], p[7]);
      asm volatile("v_permlane32_swap_b32 %0, %1" : "+v"(wA0), "+v"(wA2));
      asm volatile("v_permlane32_swap_b32 %0, %1" : "+v"(wA1), "+v"(wA3));
      u32 wB0 = cvtpk2(p[8], p[9]), wB1 = cvtpk2(p[10], p[11]);
      u32 wB2 = cvtpk2(p[12], p[13]), wB3 = cvtpk2(p[14], p[15]);
      asm volatile("v_permlane32_swap_b32 %0, %1" : "+v"(wB0), "+v"(wB2));
      asm volatile("v_permlane32_swap_b32 %0, %1" : "+v"(wB1), "+v"(wB3));
      i32x4 bi0 = {(int)wA0, (int)wA1, (int)wA2, (int)wA3};
      i32x4 bi1 = {(int)wB0, (int)wB1, (int)wB2, (int)wB3};
      bf16x8 pb0 = __builtin_bit_cast(bf16x8, bi0);
      bf16x8 pb1 = __builtin_bit_cast(bf16x8, bi1);
      #pragma unroll
      for (int dt = 0; dt < 2; ++dt) {
        o[qt][dt] = MFMA32(vf[dt][0], pb0, o[qt][dt]);
        o[qt][dt] = MFMA32(vf[dt][1], pb1, o[qt][dt]);
      }
    }
  };

  // 2-deep software pipeline: named buffers (no runtime-indexed arrays)
  bf16x8 kfA[4], vfA[2][2], kfB[4], vfB[2][2];
  loadt(kfA, vfA, 0);
  int t = 0;
  #pragma unroll 1
  for (; t + 2 <= nt; t += 2) {
    loadt(kfB, vfB, t + 1);
    compute(kfA, vfA, t);
    if (t + 2 < nt) loadt(kfA, vfA, t + 2);
    compute(kfB, vfB, t + 1);
  }
  if (t < nt) compute(kfA, vfA, t);

  #pragma unroll
  for (int qt = 0; qt < 2; ++qt) {
    float ls = l[qt] + __shfl_xor(l[qt], 32);
    float inv = 1.f / ls;
    u16* outp = AO + ((long)(b * Nn + q0w + qt * 32 + ln) * Cc) + h * HDd;
    #pragma unroll
    for (int dt = 0; dt < 2; ++dt) {
      #pragma unroll
      for (int qd = 0; qd < 4; ++qd) {  // reg quad -> d = dt*32 + 8*qd + 4*hi + 0..3
        uint2 st2 = {cvtpk2(o[qt][dt][4 * qd + 0] * inv, o[qt][dt][4 * qd + 1] * inv),
                     cvtpk2(o[qt][dt][4 * qd + 2] * inv, o[qt][dt][4 * qd + 3] * inv)};
        *(uint2*)(outp + dt * 32 + 8 * qd + 4 * hi) = st2;
      }
    }
  }
}

// ---------------- CLS-row scores (one block per (b,h), atomic accumulate) ----------------
__global__ __launch_bounds__(256) void k_sco_init(float* __restrict__ sco) {
  int gid = blockIdx.x * 256 + threadIdx.x;
  if (gid < Bb * 511) sco[gid] = 0.f;
}

__global__ __launch_bounds__(256) void k_cls(const u16* __restrict__ Q, const u16* __restrict__ K,
                                             const int* __restrict__ lens, float* __restrict__ scores) {
  int bh = blockIdx.x;  // 0..383
  int b = bh / Hh;
  int t = threadIdx.x;
  int len = lens[b];
  __shared__ float qrow[64];
  __shared__ float red[256];
  const u16* Qb = Q + (long)bh * Nn * HDd;
  const u16* Kb = K + (long)bh * Nn * HDd;
  if (t < 64) qrow[t] = bf2f(Qb[t]);   // CLS query, pre-scaled (log2 domain)
  __syncthreads();
  const bf16x8* kr0 = (const bf16x8*)(Kb + t * HDd);
  const bf16x8* kr1 = (const bf16x8*)(Kb + (t + 256) * HDd);
  float d0 = 0.f, d1 = 0.f;
  #pragma unroll
  for (int c8 = 0; c8 < 8; ++c8) {
    bf16x8 kv0 = kr0[c8], kv1 = kr1[c8];
    #pragma unroll
    for (int j = 0; j < 8; ++j) {
      float qv = qrow[c8 * 8 + j];
      d0 += qv * bf2f((u16)kv0[j]);
      d1 += qv * bf2f((u16)kv1[j]);
    }
  }
  float l0 = (t < len) ? d0 : -1e9f;
  float l1 = (t + 256 < len) ? d1 : -1e9f;
  red[t] = fmaxf(l0, l1);
  __syncthreads();
  for (int ss = 128; ss > 0; ss >>= 1) {
    if (t < ss) red[t] = fmaxf(red[t], red[t + ss]);
    __syncthreads();
  }
  float mx = red[0];
  __syncthreads();
  float e0 = fexp2(l0 - mx), e1 = fexp2(l1 - mx);
  red[t] = e0 + e1;
  __syncthreads();
  for (int ss = 128; ss > 0; ss >>= 1) {
    if (t < ss) red[t] += red[t + ss];
    __syncthreads();
  }
  float w = (1.f / 12.f) / red[0];
  if (t >= 1) atomicAdd(&scores[b * 511 + (t - 1)], e0 * w);
  atomicAdd(&scores[b * 511 + (t + 255)], e1 * w);
}

// ---------------- top-k (bitonic sort 512, desc score / asc idx) ----------------
__device__ __forceinline__ bool sless(float sa, int ia, float sb, int ib) {
  return (sa > sb) || (sa == sb && ia < ib);
}

__global__ __launch_bounds__(256) void k_topk(const float* __restrict__ scores,
                                              const int* __restrict__ lens, float* __restrict__ dout) {
  int b = blockIdx.x, t = threadIdx.x;
  __shared__ float sc[512];
  __shared__ int id[512];
  float ninf = -__builtin_inff();
  int len = lens[b];
  for (int i = t; i < 512; i += 256) {
    sc[i] = (i < 511 && (i + 1) < len) ? scores[b * 511 + i] : ninf;
    id[i] = i;
  }
  for (int k = 2; k <= 512; k <<= 1) {
    for (int j = k >> 1; j > 0; j >>= 1) {
      __syncthreads();
      for (int i = t; i < 512; i += 256) {
        int ixj = i ^ j;
        if (ixj > i) {
          float si = sc[i], sj = sc[ixj];
          int ii = id[i], ij = id[ixj];
          bool up = ((i & k) == 0);
          bool dosw = up ? sless(sj, ij, si, ii) : sless(si, ii, sj, ij);
          if (dosw) {
            sc[i] = sj; sc[ixj] = si;
            id[i] = ij; id[ixj] = ii;
          }
        }
      }
    }
  }
  __syncthreads();
  int left = (int)ceilf((float)(len - 1) * 0.7f);
  const long OFF_IDX = (long)Bb * Nn * Cc + (long)Bb * BND * Cc;
  for (int p = t; p < BND; p += 256) {
    dout[OFF_IDX + (long)b * BND + p] = (p < left) ? (float)id[p] : 1e9f;
  }
  if (b == 0 && t == 0) dout[OFF_IDX + (long)Bb * BND] = (float)BND;
}

__global__ __launch_bounds__(256) void k_bcast(float* __restrict__ dout) {
  long gid = (long)blockIdx.x * 256 + threadIdx.x;
  const long total = (long)Bb * BND * (Cc / 4);
  if (gid >= total) return;
  long bp = gid / (Cc / 4);
  int c4 = (int)(gid % (Cc / 4));
  const long OFF_INDEX = (long)Bb * Nn * Cc;
  const long OFF_IDX = OFF_INDEX + (long)Bb * BND * Cc;
  float v = dout[OFF_IDX + bp];
  float4 f = {v, v, v, v};
  *(float4*)&dout[OFF_INDEX + bp * Cc + (long)c4 * 4] = f;
}

// ---------------- launch ----------------
extern "C" void kernel_launch(void* const* d_in, const int* in_sizes, int n_in,
                              void* d_out, int out_size, void* d_ws, size_t ws_size,
                              hipStream_t stream) {
  const float* x = (const float*)d_in[0];
  const int* mask = (const int*)d_in[1];
  const float* wqkv = (const float*)d_in[2];
  const float* wproj = (const float*)d_in[3];
  const float* bproj = (const float*)d_in[4];
  float* out = (float*)d_out;

  char* ws = (char*)d_ws;
  u16* Qw  = (u16*)(ws);                    // 25165824 B
  u16* Kw  = (u16*)(ws + 25165824L);        // 25165824 B
  u16* Vtw = (u16*)(ws + 50331648L);        // 25165824 B (tiled layout)
  u16* XB  = (u16*)(ws + 75497472L);        // 25165824 B (x bf16; reused as attn out)
  u16* AO  = XB;
  u16* WQT = (u16*)(ws + 100663296L);       // 3538944 B
  u16* WPT = (u16*)(ws + 104202240L);       // 1179648 B
  float* SCO = (float*)(ws + 105381888L);   // 65536 B
  int* LEN = (int*)(ws + 105447424L);       // 128 B
  int* ORD = (int*)(ws + 105447552L);       // 128 B

  k_convx<<<12288, 256, 0, stream>>>(x, XB);
  k_transpose<<<dim3(72, 24), 256, 0, stream>>>(wqkv, WQT, 768, 2304);
  k_transpose<<<dim3(24, 24), 256, 0, stream>>>(wproj, WPT, 768, 768);
  k_lens<<<32, 256, 0, stream>>>(mask, LEN);
  k_order<<<1, 64, 0, stream>>>(LEN, ORD);
  k_sco_init<<<64, 256, 0, stream>>>(SCO);
  k_gemm2<0, 1><<<dim3(128, 12), 256, 0, stream>>>(XB, WQT, 0, Qw, Kw, nullptr, nullptr, nullptr);
  k_gemm2<0, 0><<<dim3(128, 6), 256, 0, stream>>>(XB, WQT, 1536, nullptr, nullptr, Vtw, nullptr, nullptr);
  k_attn<<<3072, 64, 0, stream>>>(Qw, Kw, Vtw, LEN, ORD, AO);
  k_gemm2<1, 0><<<dim3(128, 6), 256, 0, stream>>>(AO, WPT, 0, nullptr, nullptr, nullptr, out, bproj);
  k_cls<<<384, 256, 0, stream>>>(Qw, Kw, LEN, SCO);
  k_topk<<<32, 256, 0, stream>>>(SCO, LEN, out);
  k_bcast<<<8592, 256, 0, stream>>>(out);
}